// Round 8
// baseline (372.303 us; speedup 1.0000x reference)
//
#include <hip/hip_runtime.h>

#define NHID   512
#define NCLS   250
#define CHUNK  200
#define NTOK   2048
#define NOUT   (NCLS + CHUNK)    // 450
#define NTHR   128               // 2 waves
#define MAXTOK 32

__global__ void scatter_kernel(const int* __restrict__ cls_idx,
                               int* __restrict__ cnt,
                               int* __restrict__ list) {
    int i = blockIdx.x * blockDim.x + threadIdx.x;
    if (i < NTOK) {
        int c = cls_idx[i];
        int p = atomicAdd(&cnt[c], 1);
        if (p < MAXTOK) list[c * MAXTOK + p] = i;
    }
}

__global__ __launch_bounds__(NTHR)
void cbd_kernel(const float* __restrict__ x,
                const float* __restrict__ Wc,
                const float* __restrict__ bc,
                const float* __restrict__ Ww,
                const float* __restrict__ bw,
                const int*   __restrict__ cnt_ws,
                const int*   __restrict__ list_ws,
                float* __restrict__ out)
{
    const int tid = threadIdx.x;
    const int c   = blockIdx.x >> 2;
    const int q   = blockIdx.x & 3;

    int count = cnt_ws[c];
    if (count > MAXTOK) count = MAXTOK;
    if (count <= 0) return;

    // row-quarter: 113,113,112,112 rows; lane -> one output row
    const int qbase = q * 112 + (q < 2 ? q : 2);
    const int qlen  = 112 + (q < 2 ? 1 : 0);
    const bool rvalid = tid < qlen;
    const int r = qbase + (rvalid ? tid : qlen - 1);

    const int   col  = (r < CHUNK) ? (NCLS + r) : (r - CHUNK);
    const float bias = (r < CHUNK) ? bw[c * CHUNK + r] : bc[r - CHUNK];
    const float* __restrict__ wrow =
        (r < CHUNK) ? (Ww + (size_t)(c * CHUNK + r) * NHID)
                    : (Wc + (size_t)(r - CHUNK) * NHID);

    for (int tbase = 0; tbase < count; tbase += 16) {
        const int nv = min(count - tbase, 16);
        int tk[16];
        #pragma unroll
        for (int t = 0; t < 16; ++t) {
            int ti = tbase + (t < nv ? t : 0);
            tk[t] = __builtin_amdgcn_readfirstlane(list_ws[c * MAXTOK + ti]);
        }

        float acc[16];
        #pragma unroll
        for (int t = 0; t < 16; ++t) acc[t] = bias;

        // one 16-float super-block of W against all 16 tokens
        #define COMPUTE(S, W0, W1, W2, W3)                                   \
        {                                                                    \
            _Pragma("unroll")                                                \
            for (int t = 0; t < 16; ++t) {                                   \
                const float* xp = x + (size_t)tk[t] * NHID + 16 * (S);       \
                float4 xa = *(const float4*)(xp);                            \
                float4 xb = *(const float4*)(xp + 4);                        \
                float4 xc = *(const float4*)(xp + 8);                        \
                float4 xd = *(const float4*)(xp + 12);                       \
                float a = acc[t];                                            \
                a = fmaf((W0).x, xa.x, a); a = fmaf((W0).y, xa.y, a);        \
                a = fmaf((W0).z, xa.z, a); a = fmaf((W0).w, xa.w, a);        \
                a = fmaf((W1).x, xb.x, a); a = fmaf((W1).y, xb.y, a);        \
                a = fmaf((W1).z, xb.z, a); a = fmaf((W1).w, xb.w, a);        \
                a = fmaf((W2).x, xc.x, a); a = fmaf((W2).y, xc.y, a);        \
                a = fmaf((W2).z, xc.z, a); a = fmaf((W2).w, xc.w, a);        \
                a = fmaf((W3).x, xd.x, a); a = fmaf((W3).y, xd.y, a);        \
                a = fmaf((W3).z, xd.z, a); a = fmaf((W3).w, xd.w, a);        \
                acc[t] = a;                                                  \
            }                                                                \
        }

        // k-loop: 32 supers of 16 floats, explicit double buffer (no dynamic
        // register indexing — A/B named, unrolled by 2)
        float4 A0, A1, A2, A3, B0, B1, B2, B3;
        A0 = *(const float4*)(wrow);      A1 = *(const float4*)(wrow + 4);
        A2 = *(const float4*)(wrow + 8);  A3 = *(const float4*)(wrow + 12);
        for (int s = 0; s < 32; s += 2) {
            const float* wp1 = wrow + 16 * (s + 1);
            B0 = *(const float4*)(wp1);      B1 = *(const float4*)(wp1 + 4);
            B2 = *(const float4*)(wp1 + 8);  B3 = *(const float4*)(wp1 + 12);
            COMPUTE(s, A0, A1, A2, A3);
            if (s + 2 < 32) {
                const float* wp2 = wrow + 16 * (s + 2);
                A0 = *(const float4*)(wp2);      A1 = *(const float4*)(wp2 + 4);
                A2 = *(const float4*)(wp2 + 8);  A3 = *(const float4*)(wp2 + 12);
            }
            COMPUTE(s + 1, B0, B1, B2, B3);
        }
        #undef COMPUTE

        #pragma unroll
        for (int t = 0; t < 16; ++t)
            if (t < nv && rvalid)
                out[(size_t)tk[t] * NOUT + col] = acc[t];
    }
}

extern "C" void kernel_launch(void* const* d_in, const int* in_sizes, int n_in,
                              void* d_out, int out_size, void* d_ws, size_t ws_size,
                              hipStream_t stream) {
    const float* x   = (const float*)d_in[0];
    const float* Wc  = (const float*)d_in[1];
    const float* bc  = (const float*)d_in[2];
    const float* Ww  = (const float*)d_in[3];
    const float* bw  = (const float*)d_in[4];
    const int*   cls = (const int*)d_in[5];
    float* out = (float*)d_out;

    int* cnt  = (int*)d_ws;            // 256 counters (250 used)
    int* list = cnt + 256;             // 250*32 token lists

    hipMemsetAsync(cnt, 0, 256 * sizeof(int), stream);
    hipLaunchKernelGGL(scatter_kernel, dim3((NTOK + 255) / 256), dim3(256),
                       0, stream, cls, cnt, list);
    hipLaunchKernelGGL(cbd_kernel, dim3(NCLS * 4), dim3(NTHR), 0, stream,
                       x, Wc, bc, Ww, bw, cnt, list, out);
}

// Round 9
// 265.665 us; speedup vs baseline: 1.4014x; 1.4014x over previous
//
#include <hip/hip_runtime.h>

#define NHID   512
#define NCLS   250
#define CHUNK  200
#define NTOK   2048
#define NOUT   450
#define NTHR   256
#define MAXTOK 32
#define NTILE  29          // ceil(450/16)

typedef __attribute__((ext_vector_type(8))) short bf16x8;
typedef __attribute__((ext_vector_type(4))) float f32x4;

__global__ void scatter_kernel(const int* __restrict__ cls_idx,
                               int* __restrict__ cnt, int* __restrict__ list) {
    int i = blockIdx.x * blockDim.x + threadIdx.x;
    if (i < NTOK) {
        int c = cls_idx[i];
        int p = atomicAdd(&cnt[c], 1);
        if (p < MAXTOK) list[c * MAXTOK + p] = i;
    }
}

// split fp32 -> hi bf16 (truncate) + lo bf16 (truncate of exact residual)
__device__ __forceinline__ void cvt1(float f, bf16x8& hi, bf16x8& lo, int e) {
    unsigned u = __float_as_uint(f);
    hi[e] = (short)(u >> 16);
    float xh = __uint_as_float(u & 0xffff0000u);
    lo[e] = (short)(__float_as_uint(f - xh) >> 16);
}
__device__ __forceinline__ void cvt8(float4 a, float4 b, bf16x8& hi, bf16x8& lo) {
    cvt1(a.x, hi, lo, 0); cvt1(a.y, hi, lo, 1);
    cvt1(a.z, hi, lo, 2); cvt1(a.w, hi, lo, 3);
    cvt1(b.x, hi, lo, 4); cvt1(b.y, hi, lo, 5);
    cvt1(b.z, hi, lo, 6); cvt1(b.w, hi, lo, 7);
}

__global__ __launch_bounds__(NTHR, 4)
void cbd_mfma(const float* __restrict__ x,  const float* __restrict__ Wc,
              const float* __restrict__ bc, const float* __restrict__ Ww,
              const float* __restrict__ bw, const int* __restrict__ cnt_ws,
              const int* __restrict__ list_ws, float* __restrict__ out)
{
    // A-fragment store: [s(16)][quad(4)][m(16)][j(8)] shorts; lane reads l*16 B
    __shared__ short Ah[16 * 4 * 16 * 8];   // 16 KB
    __shared__ short Al[16 * 4 * 16 * 8];   // 16 KB
    __shared__ int   tok_s[MAXTOK];

    const int tid = threadIdx.x;
    const int c   = blockIdx.x >> 2;
    const int g   = blockIdx.x & 3;

    int count = cnt_ws[c];
    if (count <= 0) return;
    if (count > MAXTOK) count = MAXTOK;

    if (tid < MAXTOK) tok_s[tid] = list_ws[c * MAXTOK + tid];
    __syncthreads();

    const int l = tid & 63, p = tid >> 6, q = l >> 4, n = l & 15;
    const int nmt = (count + 15) >> 4;

    for (int mt = 0; mt < nmt; ++mt) {
        const int mbase  = mt << 4;
        const int mcount = min(count - mbase, 16);

        // ---- stage 16 tokens' x as split-bf16 A-fragments into LDS ----
        #pragma unroll
        for (int it = 0; it < 8; ++it) {
            int idx = it * NTHR + tid;          // 2048 float4 units
            int m   = idx >> 7;
            int k   = (idx & 127) << 2;
            float4 v = {0.f, 0.f, 0.f, 0.f};
            if (m < mcount)
                v = *(const float4*)&x[(size_t)tok_s[mbase + m] * NHID + k];
            unsigned u0 = __float_as_uint(v.x), u1 = __float_as_uint(v.y),
                     u2 = __float_as_uint(v.z), u3 = __float_as_uint(v.w);
            unsigned hA = (u0 >> 16) | (u1 & 0xffff0000u);
            unsigned hB = (u2 >> 16) | (u3 & 0xffff0000u);
            float r0 = v.x - __uint_as_float(u0 & 0xffff0000u);
            float r1 = v.y - __uint_as_float(u1 & 0xffff0000u);
            float r2 = v.z - __uint_as_float(u2 & 0xffff0000u);
            float r3 = v.w - __uint_as_float(u3 & 0xffff0000u);
            unsigned lA = (__float_as_uint(r0) >> 16) | (__float_as_uint(r1) & 0xffff0000u);
            unsigned lB = (__float_as_uint(r2) >> 16) | (__float_as_uint(r3) & 0xffff0000u);
            int s = k >> 5, qq = (k >> 3) & 3, j = k & 7;
            int base = ((s * 4 + qq) * 16 + m) * 8 + j;
            uint2 hv; hv.x = hA; hv.y = hB;
            uint2 lv; lv.x = lA; lv.y = lB;
            *(uint2*)&Ah[base] = hv;
            *(uint2*)&Al[base] = lv;
        }
        __syncthreads();

        // ---- this wave's two N-tiles: t0 in [g*8+p], t1 = t0+4 ----
        const int t0 = g * 8 + p;            // <= 27, lane row always valid
        const int t1 = t0 + 4;
        const int  r0  = t0 * 16 + n;
        const bool rv1 = (t1 < NTILE) && (t1 * 16 + n < NOUT);
        const int  rc1 = rv1 ? t1 * 16 + n : NOUT - 1;

        const float* wp0 = (r0 < NCLS)
            ? Wc + (size_t)r0 * NHID
            : Ww + ((size_t)c * CHUNK + r0 - NCLS) * NHID;
        const float* wp1 = (rc1 < NCLS)
            ? Wc + (size_t)rc1 * NHID
            : Ww + ((size_t)c * CHUNK + rc1 - NCLS) * NHID;
        const float bias0 = (r0  < NCLS) ? bc[r0]  : bw[c * CHUNK + r0  - NCLS];
        const float bias1 = (rc1 < NCLS) ? bc[rc1] : bw[c * CHUNK + rc1 - NCLS];
        wp0 += q * 8;
        wp1 += q * 8;

        f32x4 acc0 = {0.f, 0.f, 0.f, 0.f};
        f32x4 acc1 = {0.f, 0.f, 0.f, 0.f};

        #define LD(S, Xa, Xb, Ya, Yb) {                                   \
            const float* _p0 = wp0 + 32 * (S);                            \
            const float* _p1 = wp1 + 32 * (S);                            \
            Xa = *(const float4*)_p0; Xb = *(const float4*)(_p0 + 4);     \
            Ya = *(const float4*)_p1; Yb = *(const float4*)(_p1 + 4); }

        #define STEP(S, Xa, Xb, Ya, Yb) {                                 \
            bf16x8 ah = *(const bf16x8*)&Ah[(((S)*4 + q)*16 + n)*8];      \
            bf16x8 al = *(const bf16x8*)&Al[(((S)*4 + q)*16 + n)*8];      \
            bf16x8 bh0, bl0, bh1, bl1;                                    \
            cvt8(Xa, Xb, bh0, bl0);                                       \
            cvt8(Ya, Yb, bh1, bl1);                                       \
            acc0 = __builtin_amdgcn_mfma_f32_16x16x32_bf16(ah, bh0, acc0, 0, 0, 0); \
            acc1 = __builtin_amdgcn_mfma_f32_16x16x32_bf16(ah, bh1, acc1, 0, 0, 0); \
            acc0 = __builtin_amdgcn_mfma_f32_16x16x32_bf16(al, bh0, acc0, 0, 0, 0); \
            acc1 = __builtin_amdgcn_mfma_f32_16x16x32_bf16(al, bh1, acc1, 0, 0, 0); \
            acc0 = __builtin_amdgcn_mfma_f32_16x16x32_bf16(ah, bl0, acc0, 0, 0, 0); \
            acc1 = __builtin_amdgcn_mfma_f32_16x16x32_bf16(ah, bl1, acc1, 0, 0, 0); }

        float4 A0a, A0b, A1a, A1b, B0a, B0b, B1a, B1b, C0a, C0b, C1a, C1b;
        LD(0, A0a, A0b, A1a, A1b);
        LD(1, B0a, B0b, B1a, B1b);
        LD(2, C0a, C0b, C1a, C1b);
        for (int i = 0; i < 15; i += 3) {
            STEP(i, A0a, A0b, A1a, A1b);
            { int sn = min(i + 3, 15); LD(sn, A0a, A0b, A1a, A1b); }
            STEP(i + 1, B0a, B0b, B1a, B1b);
            { int sn = min(i + 4, 15); LD(sn, B0a, B0b, B1a, B1b); }
            STEP(i + 2, C0a, C0b, C1a, C1b);
            { int sn = min(i + 5, 15); LD(sn, C0a, C0b, C1a, C1b); }
        }
        STEP(15, A0a, A0b, A1a, A1b);
        #undef LD
        #undef STEP

        // ---- epilogue: D col = lane&15 (W row), D row m = quad*4 + reg ----
        #pragma unroll
        for (int i = 0; i < 4; ++i) {
            int m = q * 4 + i;
            if (m < mcount) {
                size_t ro = (size_t)tok_s[mbase + m] * NOUT;
                out[ro + r0] = acc0[i] + bias0;
                if (rv1) out[ro + rc1] = acc1[i] + bias1;
            }
        }

        if (mt + 1 < nmt) __syncthreads();
    }
}

extern "C" void kernel_launch(void* const* d_in, const int* in_sizes, int n_in,
                              void* d_out, int out_size, void* d_ws, size_t ws_size,
                              hipStream_t stream) {
    const float* x   = (const float*)d_in[0];
    const float* Wc  = (const float*)d_in[1];
    const float* bc  = (const float*)d_in[2];
    const float* Ww  = (const float*)d_in[3];
    const float* bw  = (const float*)d_in[4];
    const int*   cls = (const int*)d_in[5];
    float* out = (float*)d_out;

    int* cnt  = (int*)d_ws;            // 256 counters (250 used)
    int* list = cnt + 256;             // 250*32 token lists

    hipMemsetAsync(cnt, 0, 256 * sizeof(int), stream);
    hipLaunchKernelGGL(scatter_kernel, dim3((NTOK + 255) / 256), dim3(256),
                       0, stream, cls, cnt, list);
    hipLaunchKernelGGL(cbd_mfma, dim3(NCLS * 4), dim3(NTHR), 0, stream,
                       x, Wc, bc, Ww, bw, cnt, list, out);
}

// Round 10
// 200.901 us; speedup vs baseline: 1.8532x; 1.3224x over previous
//
#include <hip/hip_runtime.h>

#define NHID   512
#define NCLS   250
#define CHUNK  200
#define NTOK   2048
#define NOUT   450
#define MAXTOK 32
#define NTHR   256

#define CLS_UNITS 512               // 128 M-tiles x 4 N-groups (16 ntiles of 16 rows)
#define WRD_UNITS (NCLS * 8)        // 250 x (2 M-tiles x 4 N-groups)
#define NUNITS    (CLS_UNITS + WRD_UNITS)   // 2512
#define NBLK      ((NUNITS + 3) / 4)        // 628 blocks x 4 waves

typedef __attribute__((ext_vector_type(8))) short bf16x8;
typedef __attribute__((ext_vector_type(4))) float f32x4;

__global__ void scatter_kernel(const int* __restrict__ cls_idx,
                               int* __restrict__ cnt, int* __restrict__ list) {
    int i = blockIdx.x * blockDim.x + threadIdx.x;
    if (i < NTOK) {
        int c = cls_idx[i];
        int p = atomicAdd(&cnt[c], 1);
        if (p < MAXTOK) list[c * MAXTOK + p] = i;
    }
}

// pack hi bf16 of (e1,e0) into one uint via v_perm: result = (hi16(a)<<16)|hi16(b)
__device__ __forceinline__ unsigned hpack(unsigned a, unsigned b) {
    return __builtin_amdgcn_perm(a, b, 0x07060302u);
}

// fp32x8 -> hi/lo split bf16x8 (truncate hi; lo = truncate(exact residual))
__device__ __forceinline__ void cvt8(float4 va, float4 vb, bf16x8& h, bf16x8& l) {
    unsigned u0 = __float_as_uint(va.x), u1 = __float_as_uint(va.y);
    unsigned u2 = __float_as_uint(va.z), u3 = __float_as_uint(va.w);
    unsigned u4 = __float_as_uint(vb.x), u5 = __float_as_uint(vb.y);
    unsigned u6 = __float_as_uint(vb.z), u7 = __float_as_uint(vb.w);
    union { unsigned w[4]; bf16x8 v; } H, L;
    H.w[0] = hpack(u1, u0); H.w[1] = hpack(u3, u2);
    H.w[2] = hpack(u5, u4); H.w[3] = hpack(u7, u6);
    float r0 = va.x - __uint_as_float(u0 & 0xffff0000u);
    float r1 = va.y - __uint_as_float(u1 & 0xffff0000u);
    float r2 = va.z - __uint_as_float(u2 & 0xffff0000u);
    float r3 = va.w - __uint_as_float(u3 & 0xffff0000u);
    float r4 = vb.x - __uint_as_float(u4 & 0xffff0000u);
    float r5 = vb.y - __uint_as_float(u5 & 0xffff0000u);
    float r6 = vb.z - __uint_as_float(u6 & 0xffff0000u);
    float r7 = vb.w - __uint_as_float(u7 & 0xffff0000u);
    L.w[0] = hpack(__float_as_uint(r1), __float_as_uint(r0));
    L.w[1] = hpack(__float_as_uint(r3), __float_as_uint(r2));
    L.w[2] = hpack(__float_as_uint(r5), __float_as_uint(r4));
    L.w[3] = hpack(__float_as_uint(r7), __float_as_uint(r6));
    h = H.v; l = L.v;
}

// one wave-tile: A fragment stream (16 k-steps) against NK N-tiles
template <int NK>
__device__ __forceinline__ void ktile(const float* __restrict__ ap,
                                      const float* const* bp, f32x4* acc) {
    #pragma unroll 2
    for (int s = 0; s < 16; ++s) {
        float4 a0 = *(const float4*)(ap + s * 32);
        float4 a1 = *(const float4*)(ap + s * 32 + 4);
        bf16x8 ah, al;
        cvt8(a0, a1, ah, al);
        #pragma unroll
        for (int k = 0; k < NK; ++k) {
            float4 b0 = *(const float4*)(bp[k] + s * 32);
            float4 b1 = *(const float4*)(bp[k] + s * 32 + 4);
            bf16x8 bh, bl;
            cvt8(b0, b1, bh, bl);
            acc[k] = __builtin_amdgcn_mfma_f32_16x16x32_bf16(ah, bh, acc[k], 0, 0, 0);
            acc[k] = __builtin_amdgcn_mfma_f32_16x16x32_bf16(al, bh, acc[k], 0, 0, 0);
            acc[k] = __builtin_amdgcn_mfma_f32_16x16x32_bf16(ah, bl, acc[k], 0, 0, 0);
        }
    }
}

__global__ __launch_bounds__(NTHR, 2)
void cbd_mfma(const float* __restrict__ x,  const float* __restrict__ Wc,
              const float* __restrict__ bc, const float* __restrict__ Ww,
              const float* __restrict__ bw, const int* __restrict__ cnt_ws,
              const int* __restrict__ list_ws, float* __restrict__ out)
{
    const int unit = blockIdx.x * 4 + (threadIdx.x >> 6);
    if (unit >= NUNITS) return;
    const int l = threadIdx.x & 63;
    const int n = l & 15;        // lane's row-slot (A: token row m; B: W row)
    const int q = l >> 4;        // k-quad

    const bool is_cls = unit < CLS_UNITS;
    int c = 0, mtile, ntg, count = NTOK;
    if (is_cls) {
        mtile = unit >> 2;           // 0..127
        ntg   = unit & 3;            // 0..3 (ntiles 4*ntg..4*ntg+3)
    } else {
        int v = unit - CLS_UNITS;
        c     = v >> 3;
        int t = v & 7;
        mtile = t >> 2;              // 0..1
        ntg   = t & 3;               // groups: 0..2 full, 3 -> ntile 12 only
        count = cnt_ws[c];
        if (count > MAXTOK) count = MAXTOK;
        if (mtile * 16 >= count) return;
    }

    // ---- A side: lane's token row ----
    int tokA, tokS[4];
    bool sval[4];
    if (is_cls) {
        tokA = mtile * 16 + n;
        #pragma unroll
        for (int i = 0; i < 4; ++i) { tokS[i] = mtile * 16 + q * 4 + i; sval[i] = true; }
    } else {
        int mi = mtile * 16 + n;
        tokA = list_ws[c * MAXTOK + (mi < count ? mi : count - 1)];
        #pragma unroll
        for (int i = 0; i < 4; ++i) {
            int m = mtile * 16 + q * 4 + i;
            sval[i] = m < count;
            tokS[i] = list_ws[c * MAXTOK + (sval[i] ? m : count - 1)];
        }
    }
    const float* ap = x + (size_t)tokA * NHID + q * 8;

    // ---- B side: up to 4 N-tiles of 16 rows ----
    const float* bp[4];
    float bias[4];
    int   col[4];
    bool  rv[4];
    #pragma unroll
    for (int k = 0; k < 4; ++k) {
        int r = (ntg * 4 + k) * 16 + n;
        if (is_cls) {
            rv[k] = r < NCLS;
            int rc = rv[k] ? r : NCLS - 1;
            bp[k]   = Wc + (size_t)rc * NHID + q * 8;
            bias[k] = bc[rc];
            col[k]  = rc;
        } else {
            rv[k] = r < CHUNK;
            int rc = rv[k] ? r : CHUNK - 1;
            bp[k]   = Ww + ((size_t)c * CHUNK + rc) * NHID + q * 8;
            bias[k] = bw[c * CHUNK + rc];
            col[k]  = NCLS + rc;
        }
    }

    f32x4 acc[4] = {{0,0,0,0},{0,0,0,0},{0,0,0,0},{0,0,0,0}};
    const bool full = is_cls || (ntg < 3);
    if (full) ktile<4>(ap, bp, acc);
    else      ktile<1>(ap, bp, acc);   // word ntg==3: only ntile 12 exists

    // ---- epilogue: D col = lane&15 (W row), D row m = q*4 + reg ----
    const int nk = full ? 4 : 1;
    #pragma unroll
    for (int k = 0; k < 4; ++k) {
        if (k < nk && rv[k]) {
            #pragma unroll
            for (int i = 0; i < 4; ++i) {
                if (sval[i])
                    out[(size_t)tokS[i] * NOUT + col[k]] = acc[k][i] + bias[k];
            }
        }
    }
}

extern "C" void kernel_launch(void* const* d_in, const int* in_sizes, int n_in,
                              void* d_out, int out_size, void* d_ws, size_t ws_size,
                              hipStream_t stream) {
    const float* x   = (const float*)d_in[0];
    const float* Wc  = (const float*)d_in[1];
    const float* bc  = (const float*)d_in[2];
    const float* Ww  = (const float*)d_in[3];
    const float* bw  = (const float*)d_in[4];
    const int*   cls = (const int*)d_in[5];
    float* out = (float*)d_out;

    int* cnt  = (int*)d_ws;            // 256 counters (250 used)
    int* list = cnt + 256;             // 250*32 token lists

    hipMemsetAsync(cnt, 0, 256 * sizeof(int), stream);
    hipLaunchKernelGGL(scatter_kernel, dim3((NTOK + 255) / 256), dim3(256),
                       0, stream, cls, cnt, list);
    hipLaunchKernelGGL(cbd_mfma, dim3(NBLK), dim3(NTHR), 0, stream,
                       x, Wc, bc, Ww, bw, cnt, list, out);
}